// Round 1
// baseline (813.221 us; speedup 1.0000x reference)
//
#include <hip/hip_runtime.h>
#include <math.h>

// ---------------------------------------------------------------------------
// GAT encoder: 3 GATConv layers (H=4,4,1) + ELU + global max pool.
// Plan: CSR-by-dst build (count/scan/scatter) once per call, then per layer:
//   gemm_att:  z = h @ W  (fp32, LDS-tiled), fused a_s/a_d epilogue
//   aggregate: per-node online softmax over incoming edges + weighted gather
// Final: encoded atomicMax segment pool + decode.
// ---------------------------------------------------------------------------

__device__ __forceinline__ float lrelu(float x) { return x > 0.f ? x : 0.2f * x; }

// ----------------------------- CSR build -----------------------------------
__global__ void k_count(const int* __restrict__ dst, int E, int* __restrict__ deg) {
    int e = blockIdx.x * 256 + threadIdx.x;
    if (e < E) atomicAdd(&deg[dst[e]], 1);
}

__global__ void k_scan(const int* __restrict__ deg, int* __restrict__ rowptr,
                       int* __restrict__ cursor, int N) {
    __shared__ int sums[1024];
    const int t = threadIdx.x;
    const int per = (N + 1023) >> 10;
    const int b0 = t * per;
    const int b1 = min(b0 + per, N);
    int s = 0;
    for (int i = b0; i < b1; i++) s += deg[i];
    sums[t] = s;
    __syncthreads();
    // Hillis-Steele inclusive scan over 1024 partials
    for (int off = 1; off < 1024; off <<= 1) {
        int v = (t >= off) ? sums[t - off] : 0;
        __syncthreads();
        sums[t] += v;
        __syncthreads();
    }
    int run = (t == 0) ? 0 : sums[t - 1];
    for (int i = b0; i < b1; i++) {
        rowptr[i] = run;
        cursor[i] = run;
        run += deg[i];
    }
    if (t == 1023) rowptr[N] = sums[1023];
}

__global__ void k_scatter(const int* __restrict__ src, const int* __restrict__ dst, int E,
                          int* __restrict__ cursor, int* __restrict__ col) {
    int e = blockIdx.x * 256 + threadIdx.x;
    if (e < E) {
        int p = atomicAdd(&cursor[dst[e]], 1);
        col[p] = src[e];
    }
}

// ----------------------------- GEMM + attention coefs -----------------------
// z[N,COLS] = X[N,K] @ W[K,COLS]; a_s[n,h] = <z[n,h,:], att_src[h,:]>, same a_d.
// 64 rows per block, 256 threads. Thread owns 4 cols x RPG rows.
template <int K, int COLS>
__global__ __launch_bounds__(256) void k_gemm_att(
    const float* __restrict__ X, const float* __restrict__ W,
    const float* __restrict__ att_src, const float* __restrict__ att_dst,
    float* __restrict__ Z, float* __restrict__ As, float* __restrict__ Ad, int N) {
    constexpr int C4 = COLS / 4;     // col-groups (threads per row-strip)
    constexpr int NG = 256 / C4;     // row groups
    constexpr int RPG = 64 / NG;     // rows per group
    constexpr int XS = 65;           // padded LDS stride
    constexpr int H = COLS / 64;
    __shared__ float xT[64 * XS];

    const int tid = threadIdx.x;
    const int c4 = tid % C4;
    const int rg = tid / C4;
    const int rbase = rg * RPG;
    const int n0 = blockIdx.x * 64;

    float4 acc[RPG];
#pragma unroll
    for (int r = 0; r < RPG; r++) acc[r] = make_float4(0.f, 0.f, 0.f, 0.f);

    for (int kb = 0; kb < K; kb += 64) {
        __syncthreads();
        // stage 64 rows x 64 k, transposed, coalesced float4 global reads
#pragma unroll
        for (int p = 0; p < 4; p++) {
            const int lin = p * 256 + tid;
            const int r = lin >> 4;
            const int f4 = lin & 15;
            float4 v = make_float4(0.f, 0.f, 0.f, 0.f);
            const int row = n0 + r;
            if (row < N)
                v = *reinterpret_cast<const float4*>(X + (size_t)row * K + kb + f4 * 4);
            xT[(f4 * 4 + 0) * XS + r] = v.x;
            xT[(f4 * 4 + 1) * XS + r] = v.y;
            xT[(f4 * 4 + 2) * XS + r] = v.z;
            xT[(f4 * 4 + 3) * XS + r] = v.w;
        }
        __syncthreads();
#pragma unroll 8
        for (int kk = 0; kk < 64; kk++) {
            const float4 wv =
                *reinterpret_cast<const float4*>(W + (size_t)(kb + kk) * COLS + c4 * 4);
#pragma unroll
            for (int r = 0; r < RPG; r++) {
                const float xv = xT[kk * XS + rbase + r];
                acc[r].x = fmaf(xv, wv.x, acc[r].x);
                acc[r].y = fmaf(xv, wv.y, acc[r].y);
                acc[r].z = fmaf(xv, wv.z, acc[r].z);
                acc[r].w = fmaf(xv, wv.w, acc[r].w);
            }
        }
    }

    const float4 as4 = *reinterpret_cast<const float4*>(att_src + c4 * 4);
    const float4 ad4 = *reinterpret_cast<const float4*>(att_dst + c4 * 4);

#pragma unroll
    for (int r = 0; r < RPG; r++) {
        const int row = n0 + rbase + r;
        float ps = acc[r].x * as4.x + acc[r].y * as4.y + acc[r].z * as4.z + acc[r].w * as4.w;
        float pd = acc[r].x * ad4.x + acc[r].y * ad4.y + acc[r].z * ad4.z + acc[r].w * ad4.w;
        // reduce across the 16 col-threads of this head (shfl groups stay in-head)
#pragma unroll
        for (int off = 1; off < 16; off <<= 1) {
            ps += __shfl_xor(ps, off, 64);
            pd += __shfl_xor(pd, off, 64);
        }
        if (row < N) {
            *reinterpret_cast<float4*>(Z + (size_t)row * COLS + c4 * 4) = acc[r];
            if ((c4 & 15) == 0) {
                As[(size_t)row * H + (c4 >> 4)] = ps;
                Ad[(size_t)row * H + (c4 >> 4)] = pd;
            }
        }
    }
}

// ----------------------------- softmax + aggregate ---------------------------
// One block (256 thr) per destination node. Self-loop is virtual edge idx==deg.
template <int H, bool DO_ELU>
__global__ __launch_bounds__(256) void k_aggregate(
    const float* __restrict__ Z, const float* __restrict__ As, const float* __restrict__ Ad,
    const int* __restrict__ rowptr, const int* __restrict__ col,
    const float* __restrict__ bias, float* __restrict__ out, int N) {
    constexpr int COLS = H * 64;
    const int n = blockIdx.x;
    const int tid = threadIdx.x;
    const int start = rowptr[n];
    const int deg = rowptr[n + 1] - start;
    const int total = deg + 1;

    float adn[H];
#pragma unroll
    for (int h = 0; h < H; h++) adn[h] = Ad[(size_t)n * H + h];

    // Phase A: per-head max over incoming edges
    float m[H];
#pragma unroll
    for (int h = 0; h < H; h++) m[h] = -INFINITY;
    for (int i = tid; i < total; i += 256) {
        const int s = (i < deg) ? col[start + i] : n;
        if constexpr (H == 4) {
            const float4 av = *reinterpret_cast<const float4*>(As + (size_t)s * 4);
            m[0] = fmaxf(m[0], lrelu(av.x + adn[0]));
            m[1] = fmaxf(m[1], lrelu(av.y + adn[1]));
            m[2] = fmaxf(m[2], lrelu(av.z + adn[2]));
            m[3] = fmaxf(m[3], lrelu(av.w + adn[3]));
        } else {
            m[0] = fmaxf(m[0], lrelu(As[s] + adn[0]));
        }
    }
#pragma unroll
    for (int h = 0; h < H; h++) {
#pragma unroll
        for (int off = 1; off < 64; off <<= 1) m[h] = fmaxf(m[h], __shfl_xor(m[h], off, 64));
    }
    __shared__ float mred[4][H];
    const int wid = tid >> 6;
    const int lane = tid & 63;
    if (lane == 0) {
#pragma unroll
        for (int h = 0; h < H; h++) mred[wid][h] = m[h];
    }
    __syncthreads();
#pragma unroll
    for (int h = 0; h < H; h++)
        m[h] = fmaxf(fmaxf(mred[0][h], mred[1][h]), fmaxf(mred[2][h], mred[3][h]));

    // Phase B: chunked exp + denom + weighted gather (unnormalized, divide at end)
    __shared__ float w_lds[64][H];
    __shared__ int src_lds[64];

    float acc = 0.f, denom = 0.f;
    const int h = (H == 4) ? (tid >> 6) : 0;
    const int c = tid & 63;
    const int q = tid >> 6;

    for (int base = 0; base < total; base += 64) {
        const int cnt = min(64, total - base);
        __syncthreads();
        if (tid < cnt) {
            const int i = base + tid;
            const int s = (i < deg) ? col[start + i] : n;
            src_lds[tid] = s;
            if constexpr (H == 4) {
                const float4 av = *reinterpret_cast<const float4*>(As + (size_t)s * 4);
                w_lds[tid][0] = expf(lrelu(av.x + adn[0]) - m[0]);
                w_lds[tid][1] = expf(lrelu(av.y + adn[1]) - m[1]);
                w_lds[tid][2] = expf(lrelu(av.z + adn[2]) - m[2]);
                w_lds[tid][3] = expf(lrelu(av.w + adn[3]) - m[3]);
            } else {
                w_lds[tid][0] = expf(lrelu(As[s] + adn[0]) - m[0]);
            }
        }
        __syncthreads();
        if constexpr (H == 4) {
            for (int j = 0; j < cnt; j++) {
                const int s = src_lds[j];
                const float wj = w_lds[j][h];
                acc = fmaf(wj, Z[(size_t)s * COLS + tid], acc);
                denom += wj;
            }
        } else {
            for (int j = q; j < cnt; j += 4) {
                const int s = src_lds[j];
                const float wj = w_lds[j][0];
                acc = fmaf(wj, Z[(size_t)s * 64 + c], acc);
                denom += wj;
            }
        }
    }

    if constexpr (H == 4) {
        float ov = acc / (denom + 1e-16f) + bias[tid];
        if (DO_ELU) ov = (ov > 0.f) ? ov : expm1f(ov);
        out[(size_t)n * COLS + tid] = ov;
    } else {
        __shared__ float accr[4][64];
        __shared__ float denr[4];
        accr[q][c] = acc;
        if (c == 0) denr[q] = denom;
        __syncthreads();
        if (tid < 64) {
            float tot = accr[0][tid] + accr[1][tid] + accr[2][tid] + accr[3][tid];
            float den = denr[0] + denr[1] + denr[2] + denr[3];
            float ov = tot / (den + 1e-16f) + bias[tid];
            if (DO_ELU) ov = (ov > 0.f) ? ov : expm1f(ov);
            out[(size_t)n * 64 + tid] = ov;
        }
    }
}

// ----------------------------- global max pool ------------------------------
__device__ __forceinline__ unsigned fenc(float f) {
    unsigned u = __float_as_uint(f);
    return (u & 0x80000000u) ? ~u : (u | 0x80000000u);
}

__global__ void k_segmax(const float* __restrict__ h2, const int* __restrict__ batch, int N,
                         unsigned* __restrict__ enc) {
    int id = blockIdx.x * 256 + threadIdx.x;
    if (id < N * 64) {
        int nn = id >> 6;
        int c = id & 63;
        int g = batch[nn];
        atomicMax(&enc[g * 64 + c], fenc(h2[id]));
    }
}

__global__ void k_decode(const unsigned* __restrict__ enc, float* __restrict__ out, int M) {
    int id = blockIdx.x * 256 + threadIdx.x;
    if (id < M) {
        unsigned e = enc[id];
        unsigned u = (e & 0x80000000u) ? (e & 0x7FFFFFFFu) : ~e;
        out[id] = __uint_as_float(u);
    }
}

// ----------------------------- launch ---------------------------------------
extern "C" void kernel_launch(void* const* d_in, const int* in_sizes, int n_in,
                              void* d_out, int out_size, void* d_ws, size_t ws_size,
                              hipStream_t stream) {
    const float* x = (const float*)d_in[0];
    const int* edge_index = (const int*)d_in[1];
    const int* batch = (const int*)d_in[2];
    const float* W0 = (const float*)d_in[3];
    const float* as0 = (const float*)d_in[4];
    const float* ad0 = (const float*)d_in[5];
    const float* b0 = (const float*)d_in[6];
    const float* W1 = (const float*)d_in[7];
    const float* as1 = (const float*)d_in[8];
    const float* ad1 = (const float*)d_in[9];
    const float* b1 = (const float*)d_in[10];
    const float* W2 = (const float*)d_in[11];
    const float* as2 = (const float*)d_in[12];
    const float* ad2 = (const float*)d_in[13];
    const float* b2 = (const float*)d_in[14];

    const int N = in_sizes[0] / 64;   // nodes
    const int E = in_sizes[1] / 2;    // edges (no self-loops)
    const int G = out_size / 64;      // graphs

    const int* srcs = edge_index;
    const int* dsts = edge_index + E;

    char* p = (char*)d_ws;
    auto alloc = [&](size_t bytes) {
        void* r = (void*)p;
        p += (bytes + 255) & ~(size_t)255;
        return r;
    };
    float* Z  = (float*)alloc((size_t)N * 256 * 4);  // z buffer (layer output of GEMM)
    float* Hb = (float*)alloc((size_t)N * 256 * 4);  // hidden activations
    float* As = (float*)alloc((size_t)N * 4 * 4);
    float* Ad = (float*)alloc((size_t)N * 4 * 4);
    int* deg = (int*)alloc((size_t)N * 4);
    int* rowptr = (int*)alloc((size_t)(N + 1) * 4);
    int* cursor = (int*)alloc((size_t)N * 4);
    int* col = (int*)alloc((size_t)E * 4);
    unsigned* enc = (unsigned*)alloc((size_t)G * 64 * 4);

    hipMemsetAsync(deg, 0, (size_t)N * 4, stream);
    hipMemsetAsync(enc, 0, (size_t)G * 64 * 4, stream);

    const int eb = (E + 255) / 256;
    k_count<<<eb, 256, 0, stream>>>(dsts, E, deg);
    k_scan<<<1, 1024, 0, stream>>>(deg, rowptr, cursor, N);
    k_scatter<<<eb, 256, 0, stream>>>(srcs, dsts, E, cursor, col);

    const int gb = (N + 63) / 64;
    // Layer 0: in 64, H=4 concat -> 256, ELU
    k_gemm_att<64, 256><<<gb, 256, 0, stream>>>(x, W0, as0, ad0, Z, As, Ad, N);
    k_aggregate<4, true><<<N, 256, 0, stream>>>(Z, As, Ad, rowptr, col, b0, Hb, N);
    // Layer 1: in 256, H=4 concat -> 256, ELU
    k_gemm_att<256, 256><<<gb, 256, 0, stream>>>(Hb, W1, as1, ad1, Z, As, Ad, N);
    k_aggregate<4, true><<<N, 256, 0, stream>>>(Z, As, Ad, rowptr, col, b1, Hb, N);
    // Layer 2: in 256, H=1 -> 64, no ELU
    k_gemm_att<256, 64><<<gb, 256, 0, stream>>>(Hb, W2, as2, ad2, Z, As, Ad, N);
    k_aggregate<1, false><<<N, 256, 0, stream>>>(Z, As, Ad, rowptr, col, b2, Hb, N);
    // Global max pool
    k_segmax<<<(N * 64 + 255) / 256, 256, 0, stream>>>(Hb, batch, N, enc);
    k_decode<<<(G * 64 + 255) / 256, 256, 0, stream>>>(enc, (float*)d_out, G * 64);
}